// Round 1
// baseline (541.111 us; speedup 1.0000x reference)
//
#include <hip/hip_runtime.h>

// CustomAttention: out = softmax((x_t Wq^T + bq)(x_nt Wk^T + bk)^T) (x_nt Wv^T + bv)
// B=8, SQ=SKV=2048, D=1024. fp32 in/out, fp16 MFMA compute (fp32 accumulate).
//
// Pipeline (all on `stream`):
//  1. cast fp32->fp16: target, non_target, Wq, Wk, Wv
//  2. GEMM (BT layout) -> Q16 [16384,1024], K16 [16384,1024], Vt16 [8][1024][2048] (transposed)
//  3. batched GEMM Q16*K16^T -> S fp32 [8][2048][2048]
//  4. row softmax S -> P fp16 [8][2048][2048]
//  5. batched GEMM P*Vt^T -> d_out fp32
//
// ws layout (230 MiB peak, with dead-region aliasing):
//  [0,32)    tgt16      -- dead after phase 2 ┐
//  [32,64)   ntg16      -- dead after phase 2 ┘ S [0,128) written phase 3
//  [64,128)  (S tail)
//  [128,160) Q16        -- dead after QK ┐ P16 [128,192) written phase 4
//  [160,192) K16        -- dead after QK ┘
//  [192,224) Vt16
//  [224,230) Wq16/Wk16/Wv16

typedef _Float16 half8 __attribute__((ext_vector_type(8)));
typedef _Float16 half4v __attribute__((ext_vector_type(4)));
typedef float floatx4 __attribute__((ext_vector_type(4)));

__device__ __forceinline__ void async_copy16(const _Float16* g, _Float16* l) {
  __builtin_amdgcn_global_load_lds(
      (const __attribute__((address_space(1))) void*)g,
      (__attribute__((address_space(3))) void*)l,
      16, 0, 0);
}

// ---------------- cast fp32 -> fp16 (8 elems/thread) ----------------
__global__ __launch_bounds__(256) void cast_f32_f16(const float* __restrict__ src,
                                                    _Float16* __restrict__ dst, long n) {
  long i = ((long)blockIdx.x * 256 + threadIdx.x) * 8;
  if (i >= n) return;
  float4 a = *(const float4*)(src + i);
  float4 b = *(const float4*)(src + i + 4);
  half8 h;
  h[0] = (_Float16)a.x; h[1] = (_Float16)a.y; h[2] = (_Float16)a.z; h[3] = (_Float16)a.w;
  h[4] = (_Float16)b.x; h[5] = (_Float16)b.y; h[6] = (_Float16)b.z; h[7] = (_Float16)b.w;
  *(half8*)(dst + i) = h;
}

// ---------------- fp16 BT GEMM: C[m,n] = sum_k A[m,k]*B[n,k] (+bias[n]) ----------------
// 128x128 tile, BK=32, 256 threads = 4 waves in 2x2 of 64x64, 16x16x32 fp16 MFMA.
// m97 structure: global_load_lds width=16 staging, 2-barrier K-loop,
// ds_read_b128 fragment loads (A-frag: lane holds A[m=lane&15][k=(lane>>4)*8+j]).
// OMODE 0: fp16 out row-major [*,N] + bias
// OMODE 1: fp16 out V-transposed: row r -> (b=r>>11, s=r&2047), store Vt[b][n][s], + bias
// OMODE 2: fp32 out row-major [*,N] per batch (no bias)
template <int OMODE>
__global__ __launch_bounds__(256, 2) void gemm_bt(const _Float16* __restrict__ A,
                                                  const _Float16* __restrict__ B,
                                                  const float* __restrict__ bias,
                                                  void* __restrict__ out,
                                                  int K, int N,
                                                  long sA, long sB, long sO) {
  __shared__ __attribute__((aligned(16))) _Float16 As[128 * 32];
  __shared__ __attribute__((aligned(16))) _Float16 Bs[128 * 32];

  const int tid = threadIdx.x;
  const int lane = tid & 63;
  const int wave = tid >> 6;
  const long bz = blockIdx.z;

  const _Float16* Ab = A + bz * sA + (long)blockIdx.x * 128 * K;
  const _Float16* Bb = B + bz * sB + (long)blockIdx.y * 128 * K;

  const int wm = (wave & 1) * 64;   // wave m-offset within tile
  const int wn = (wave >> 1) * 64;  // wave n-offset
  const int frow = lane & 15;       // fragment row/col
  const int fq = lane >> 4;         // fragment quad (k-group)

  floatx4 acc[4][4];
#pragma unroll
  for (int mt = 0; mt < 4; mt++)
#pragma unroll
    for (int nt = 0; nt < 4; nt++)
      acc[mt][nt] = (floatx4){0.f, 0.f, 0.f, 0.f};

  // staging: tile is 128 rows x 64B; 16B chunks: chunk c -> row c>>2, halfs (c&3)*8
  const int c0 = tid, c1 = tid + 256;
  const int ar0 = c0 >> 2, ao0 = (c0 & 3) * 8;
  const int ar1 = c1 >> 2, ao1 = (c1 & 3) * 8;

  for (int k0 = 0; k0 < K; k0 += 32) {
    __syncthreads();  // previous iter's LDS reads complete before overwrite
    async_copy16(Ab + (long)ar0 * K + k0 + ao0, As + c0 * 8);
    async_copy16(Ab + (long)ar1 * K + k0 + ao1, As + c1 * 8);
    async_copy16(Bb + (long)ar0 * K + k0 + ao0, Bs + c0 * 8);
    async_copy16(Bb + (long)ar1 * K + k0 + ao1, Bs + c1 * 8);
    __syncthreads();  // vmcnt(0) drain before barrier -> LDS visible

    half8 af[4], bf[4];
#pragma unroll
    for (int mt = 0; mt < 4; mt++)
      af[mt] = *(const half8*)(As + (wm + mt * 16 + frow) * 32 + fq * 8);
#pragma unroll
    for (int nt = 0; nt < 4; nt++)
      bf[nt] = *(const half8*)(Bs + (wn + nt * 16 + frow) * 32 + fq * 8);
#pragma unroll
    for (int mt = 0; mt < 4; mt++)
#pragma unroll
      for (int nt = 0; nt < 4; nt++)
        acc[mt][nt] = __builtin_amdgcn_mfma_f32_16x16x32_f16(af[mt], bf[nt], acc[mt][nt], 0, 0, 0);
  }

  // C/D layout (verified, dtype-independent): acc[mt][nt][i] = C[wm+mt*16+fq*4+i][wn+nt*16+frow]
  if (OMODE == 2) {
    float* O = (float*)out + bz * sO;
#pragma unroll
    for (int nt = 0; nt < 4; nt++) {
      const int n = blockIdx.y * 128 + wn + nt * 16 + frow;
#pragma unroll
      for (int mt = 0; mt < 4; mt++) {
        const int rbase = blockIdx.x * 128 + wm + mt * 16 + fq * 4;
#pragma unroll
        for (int i = 0; i < 4; i++)
          O[(long)(rbase + i) * N + n] = acc[mt][nt][i];
      }
    }
  } else {
#pragma unroll
    for (int nt = 0; nt < 4; nt++) {
      const int n = blockIdx.y * 128 + wn + nt * 16 + frow;
      const float bv = bias[n];
#pragma unroll
      for (int mt = 0; mt < 4; mt++) {
        const int rbase = blockIdx.x * 128 + wm + mt * 16 + fq * 4;
#pragma unroll
        for (int i = 0; i < 4; i++) {
          const float v = acc[mt][nt][i] + bv;
          if (OMODE == 0) {
            ((_Float16*)out)[(long)(rbase + i) * N + n] = (_Float16)v;
          } else {  // V transposed: Vt[b][n][s]
            const int r = rbase + i;
            const long bb = r >> 11;
            const int s = r & 2047;
            ((_Float16*)out)[bb * (2048l * 1024) + (long)n * 2048 + s] = (_Float16)v;
          }
        }
      }
    }
  }
}

// ---------------- row softmax: S fp32 [rows][2048] -> P fp16 ----------------
__global__ __launch_bounds__(256) void softmax_rows(const float* __restrict__ S,
                                                    _Float16* __restrict__ P) {
  const long row = blockIdx.x;
  const float* src = S + row * 2048;
  _Float16* dst = P + row * 2048;
  const int tid = threadIdx.x;

  float4 v0 = ((const float4*)src)[tid];        // elems 4t..4t+3
  float4 v1 = ((const float4*)src)[tid + 256];  // elems 1024+4t..

  float m = fmaxf(fmaxf(fmaxf(v0.x, v0.y), fmaxf(v0.z, v0.w)),
                  fmaxf(fmaxf(v1.x, v1.y), fmaxf(v1.z, v1.w)));
#pragma unroll
  for (int o = 32; o > 0; o >>= 1) m = fmaxf(m, __shfl_xor(m, o, 64));
  __shared__ float redm[4];
  if ((tid & 63) == 0) redm[tid >> 6] = m;
  __syncthreads();
  m = fmaxf(fmaxf(redm[0], redm[1]), fmaxf(redm[2], redm[3]));

  float e[8];
  e[0] = __expf(v0.x - m); e[1] = __expf(v0.y - m);
  e[2] = __expf(v0.z - m); e[3] = __expf(v0.w - m);
  e[4] = __expf(v1.x - m); e[5] = __expf(v1.y - m);
  e[6] = __expf(v1.z - m); e[7] = __expf(v1.w - m);
  float s = ((e[0] + e[1]) + (e[2] + e[3])) + ((e[4] + e[5]) + (e[6] + e[7]));
#pragma unroll
  for (int o = 32; o > 0; o >>= 1) s += __shfl_xor(s, o, 64);
  __shared__ float reds[4];
  if ((tid & 63) == 0) reds[tid >> 6] = s;
  __syncthreads();
  s = (reds[0] + reds[1]) + (reds[2] + reds[3]);
  const float inv = 1.f / s;

  half4v h0, h1;
  h0[0] = (_Float16)(e[0] * inv); h0[1] = (_Float16)(e[1] * inv);
  h0[2] = (_Float16)(e[2] * inv); h0[3] = (_Float16)(e[3] * inv);
  h1[0] = (_Float16)(e[4] * inv); h1[1] = (_Float16)(e[5] * inv);
  h1[2] = (_Float16)(e[6] * inv); h1[3] = (_Float16)(e[7] * inv);
  *(half4v*)(dst + tid * 4) = h0;
  *(half4v*)(dst + 1024 + tid * 4) = h1;
}

extern "C" void kernel_launch(void* const* d_in, const int* in_sizes, int n_in,
                              void* d_out, int out_size, void* d_ws, size_t ws_size,
                              hipStream_t stream) {
  const float* target = (const float*)d_in[0];
  const float* non_target = (const float*)d_in[1];
  const float* Wq = (const float*)d_in[2];
  const float* bq = (const float*)d_in[3];
  const float* Wk = (const float*)d_in[4];
  const float* bk = (const float*)d_in[5];
  const float* Wv = (const float*)d_in[6];
  const float* bv = (const float*)d_in[7];

  char* ws = (char*)d_ws;
  const size_t MB = 1ull << 20;
  _Float16* tgt16 = (_Float16*)(ws);             // 32 MiB
  _Float16* ntg16 = (_Float16*)(ws + 32 * MB);   // 32 MiB
  float* S = (float*)(ws);                       // 128 MiB (over tgt16/ntg16, phase 3)
  _Float16* Q16 = (_Float16*)(ws + 128 * MB);    // 32 MiB
  _Float16* K16 = (_Float16*)(ws + 160 * MB);    // 32 MiB
  _Float16* P16 = (_Float16*)(ws + 128 * MB);    // 64 MiB (over Q16/K16, phase 4)
  _Float16* Vt16 = (_Float16*)(ws + 192 * MB);   // 32 MiB
  _Float16* Wq16 = (_Float16*)(ws + 224 * MB);   // 2 MiB
  _Float16* Wk16 = (_Float16*)(ws + 226 * MB);   // 2 MiB
  _Float16* Wv16 = (_Float16*)(ws + 228 * MB);   // 2 MiB

  const long nBig = 8l * 2048 * 1024;   // 16.78M
  const long nW = 1024l * 1024;

  // 1. casts
  cast_f32_f16<<<8192, 256, 0, stream>>>(target, tgt16, nBig);
  cast_f32_f16<<<8192, 256, 0, stream>>>(non_target, ntg16, nBig);
  cast_f32_f16<<<512, 256, 0, stream>>>(Wq, Wq16, nW);
  cast_f32_f16<<<512, 256, 0, stream>>>(Wk, Wk16, nW);
  cast_f32_f16<<<512, 256, 0, stream>>>(Wv, Wv16, nW);

  // 2. projections: [16384,1024] = [16384,1024] x [1024,1024]^T + bias
  gemm_bt<0><<<dim3(128, 8, 1), 256, 0, stream>>>(tgt16, Wq16, bq, Q16, 1024, 1024, 0, 0, 0);
  gemm_bt<0><<<dim3(128, 8, 1), 256, 0, stream>>>(ntg16, Wk16, bk, K16, 1024, 1024, 0, 0, 0);
  gemm_bt<1><<<dim3(128, 8, 1), 256, 0, stream>>>(ntg16, Wv16, bv, Vt16, 1024, 1024, 0, 0, 0);

  // 3. scores: per batch [2048,2048] = Q_b x K_b^T (fp32 out)
  gemm_bt<2><<<dim3(16, 16, 8), 256, 0, stream>>>(Q16, K16, nullptr, S, 1024, 2048,
                                                  2048l * 1024, 2048l * 1024, 2048l * 2048);

  // 4. softmax rows -> P fp16
  softmax_rows<<<16384, 256, 0, stream>>>(S, P16);

  // 5. out: per batch [2048,1024] = P_b x Vt_b^T (fp32 out to d_out)
  gemm_bt<2><<<dim3(16, 8, 8), 256, 0, stream>>>(P16, Vt16, nullptr, (float*)d_out, 2048, 1024,
                                                 2048l * 2048, 1024l * 2048, 2048l * 1024);
}

// Round 2
// 477.528 us; speedup vs baseline: 1.1332x; 1.1332x over previous
//
#include <hip/hip_runtime.h>

// CustomAttention: out = softmax((x_t Wq^T + bq)(x_nt Wk^T + bk)^T) (x_nt Wv^T + bv)
// B=8, SQ=SKV=2048, D=1024. fp32 in/out, fp16 MFMA compute (fp32 accumulate).
//
// Round 2 changes vs round 1 (541 us, QK/PV ~100 us @ 28% MfmaUtil, 8.4e6 LDS conflicts):
//  - BK=64 K-tile (halves barrier drains; 32 KB LDS, VGPR-limited occupancy unchanged)
//  - XOR-swizzled LDS granule layout: global_load_lds dest is forced to
//    base+lane*16, but the GLOBAL address per lane is free -> permute fetched
//    granule (g ^ (row&7)) so ds_read_b128 fragment loads are 2-way (free)
//    instead of 8/16-way bank-conflicted.
//  - S stored fp16 (QK write 64 MB not 136; softmax reads fp16)
//  - Vt epilogue packs 4 halfs -> one 8B store
//
// ws layout (224 MiB peak + 6 MiB weights):
//  [0,32)    tgt16   -- dead after projections ┐ S16 [0,64) written by QK
//  [32,64)   ntg16   -- dead after projections ┘
//  [64,128)  P16     (written by softmax)
//  [128,160) Q16
//  [160,192) K16
//  [192,224) Vt16
//  [224,230) Wq16/Wk16/Wv16

typedef _Float16 half8 __attribute__((ext_vector_type(8)));
typedef _Float16 half4v __attribute__((ext_vector_type(4)));
typedef float floatx4 __attribute__((ext_vector_type(4)));

__device__ __forceinline__ void async_copy16(const _Float16* g, _Float16* l) {
  __builtin_amdgcn_global_load_lds(
      (const __attribute__((address_space(1))) void*)g,
      (__attribute__((address_space(3))) void*)l,
      16, 0, 0);
}

// ---------------- cast fp32 -> fp16 (8 elems/thread) ----------------
__global__ __launch_bounds__(256) void cast_f32_f16(const float* __restrict__ src,
                                                    _Float16* __restrict__ dst, long n) {
  long i = ((long)blockIdx.x * 256 + threadIdx.x) * 8;
  if (i >= n) return;
  float4 a = *(const float4*)(src + i);
  float4 b = *(const float4*)(src + i + 4);
  half8 h;
  h[0] = (_Float16)a.x; h[1] = (_Float16)a.y; h[2] = (_Float16)a.z; h[3] = (_Float16)a.w;
  h[4] = (_Float16)b.x; h[5] = (_Float16)b.y; h[6] = (_Float16)b.z; h[7] = (_Float16)b.w;
  *(half8*)(dst + i) = h;
}

// ---------------- fp16 BT GEMM: C[m,n] = sum_k A[m,k]*B[n,k] (+bias[n]) ----------------
// 128x128 tile, BK=64, 256 threads = 4 waves in 2x2 of 64x64, 16x16x32 fp16 MFMA.
// LDS tile: 128 rows x 8 granules (granule = 8 halfs = 16B), physical granule
// index = logical ^ (row & 7)  [XOR swizzle, conflict-free ds_read_b128].
// OMODE 0: fp16 out row-major [*,N] + bias
// OMODE 1: fp16 out V-transposed: row r -> (b=r>>11, s=r&2047), Vt[b][n][s], + bias
// OMODE 2: fp32 out row-major [*,N] per batch (no bias)
// OMODE 3: fp16 out row-major [*,N] per batch (no bias)  [S scores]
template <int OMODE>
__global__ __launch_bounds__(256, 2) void gemm_bt(const _Float16* __restrict__ A,
                                                  const _Float16* __restrict__ B,
                                                  const float* __restrict__ bias,
                                                  void* __restrict__ out,
                                                  int K, int N,
                                                  long sA, long sB, long sO) {
  __shared__ __attribute__((aligned(16))) _Float16 As[128 * 64];  // 16 KB
  __shared__ __attribute__((aligned(16))) _Float16 Bs[128 * 64];  // 16 KB

  const int tid = threadIdx.x;
  const int lane = tid & 63;
  const int wave = tid >> 6;
  const long bz = blockIdx.z;

  const _Float16* Ab = A + bz * sA + (long)blockIdx.x * 128 * K;
  const _Float16* Bb = B + bz * sB + (long)blockIdx.y * 128 * K;

  const int wm = (wave & 1) * 64;   // wave m-offset within tile
  const int wn = (wave >> 1) * 64;  // wave n-offset
  const int frow = lane & 15;       // fragment row/col
  const int fq = lane >> 4;         // fragment quad (k-group)
  const int fsw = frow & 7;         // fragment-read swizzle key

  floatx4 acc[4][4];
#pragma unroll
  for (int mt = 0; mt < 4; mt++)
#pragma unroll
    for (int nt = 0; nt < 4; nt++)
      acc[mt][nt] = (floatx4){0.f, 0.f, 0.f, 0.f};

  // Staging: 1024 16B-chunks per matrix; thread handles chunks tid+256j, j=0..3.
  // Physical chunk c -> row c>>3, phys granule c&7; fetch logical granule
  // (c&7)^(row&7). Since 256j is a multiple of 8 and 32j a multiple of 8,
  // row&7 == (tid>>3)&7 for all j -> swizzle key is j-invariant.
  const int sr = tid >> 3;                    // base row 0..31 (j adds 32j)
  const int gl = (tid & 7) ^ (sr & 7);        // logical granule to fetch
  const long gOffBase = (long)sr * K + gl * 8;
  const int ldsOff = tid * 8;                 // halfs; j adds 2048

  for (int k0 = 0; k0 < K; k0 += 64) {
    __syncthreads();  // previous iter's LDS reads complete before overwrite
#pragma unroll
    for (int j = 0; j < 4; j++) {
      async_copy16(Ab + gOffBase + (long)(32 * j) * K + k0, As + ldsOff + j * 2048);
      async_copy16(Bb + gOffBase + (long)(32 * j) * K + k0, Bs + ldsOff + j * 2048);
    }
    __syncthreads();  // vmcnt(0) drain before barrier -> LDS visible

#pragma unroll
    for (int h = 0; h < 2; h++) {
      half8 af[4], bf[4];
#pragma unroll
      for (int mt = 0; mt < 4; mt++)
        af[mt] = *(const half8*)(As + (wm + mt * 16 + frow) * 64 + ((h * 4 + fq) ^ fsw) * 8);
#pragma unroll
      for (int nt = 0; nt < 4; nt++)
        bf[nt] = *(const half8*)(Bs + (wn + nt * 16 + frow) * 64 + ((h * 4 + fq) ^ fsw) * 8);
#pragma unroll
      for (int mt = 0; mt < 4; mt++)
#pragma unroll
        for (int nt = 0; nt < 4; nt++)
          acc[mt][nt] = __builtin_amdgcn_mfma_f32_16x16x32_f16(af[mt], bf[nt], acc[mt][nt], 0, 0, 0);
    }
  }

  // C/D layout: acc[mt][nt][i] = C[wm+mt*16+fq*4+i][wn+nt*16+frow]
  if (OMODE == 2 || OMODE == 3) {
#pragma unroll
    for (int nt = 0; nt < 4; nt++) {
      const int n = blockIdx.y * 128 + wn + nt * 16 + frow;
#pragma unroll
      for (int mt = 0; mt < 4; mt++) {
        const int rbase = blockIdx.x * 128 + wm + mt * 16 + fq * 4;
#pragma unroll
        for (int i = 0; i < 4; i++) {
          if (OMODE == 2)
            ((float*)out + bz * sO)[(long)(rbase + i) * N + n] = acc[mt][nt][i];
          else
            ((_Float16*)out + bz * sO)[(long)(rbase + i) * N + n] = (_Float16)acc[mt][nt][i];
        }
      }
    }
  } else {
#pragma unroll
    for (int nt = 0; nt < 4; nt++) {
      const int n = blockIdx.y * 128 + wn + nt * 16 + frow;
      const float bvv = bias[n];
#pragma unroll
      for (int mt = 0; mt < 4; mt++) {
        const int rbase = blockIdx.x * 128 + wm + mt * 16 + fq * 4;
        if (OMODE == 0) {
#pragma unroll
          for (int i = 0; i < 4; i++)
            ((_Float16*)out)[(long)(rbase + i) * N + n] = (_Float16)(acc[mt][nt][i] + bvv);
        } else {  // OMODE 1: Vt[b][n][s], s = rbase..rbase+3 contiguous -> 8B store
          const long bb = rbase >> 11;
          const int s = rbase & 2047;
          half4v hv;
#pragma unroll
          for (int i = 0; i < 4; i++) hv[i] = (_Float16)(acc[mt][nt][i] + bvv);
          *(half4v*)((_Float16*)out + bb * (2048l * 1024) + (long)n * 2048 + s) = hv;
        }
      }
    }
  }
}

// ---------------- row softmax: S fp16 [rows][2048] -> P fp16 ----------------
__global__ __launch_bounds__(256) void softmax_rows(const _Float16* __restrict__ S,
                                                    _Float16* __restrict__ P) {
  const long row = blockIdx.x;
  const _Float16* src = S + row * 2048;
  _Float16* dst = P + row * 2048;
  const int tid = threadIdx.x;

  half8 v = ((const half8*)src)[tid];  // elems 8t..8t+7
  float f[8];
#pragma unroll
  for (int i = 0; i < 8; i++) f[i] = (float)v[i];

  float m = fmaxf(fmaxf(fmaxf(f[0], f[1]), fmaxf(f[2], f[3])),
                  fmaxf(fmaxf(f[4], f[5]), fmaxf(f[6], f[7])));
#pragma unroll
  for (int o = 32; o > 0; o >>= 1) m = fmaxf(m, __shfl_xor(m, o, 64));
  __shared__ float redm[4];
  if ((tid & 63) == 0) redm[tid >> 6] = m;
  __syncthreads();
  m = fmaxf(fmaxf(redm[0], redm[1]), fmaxf(redm[2], redm[3]));

  float e[8], s = 0.f;
#pragma unroll
  for (int i = 0; i < 8; i++) { e[i] = __expf(f[i] - m); s += e[i]; }
#pragma unroll
  for (int o = 32; o > 0; o >>= 1) s += __shfl_xor(s, o, 64);
  __shared__ float reds[4];
  if ((tid & 63) == 0) reds[tid >> 6] = s;
  __syncthreads();
  s = (reds[0] + reds[1]) + (reds[2] + reds[3]);
  const float inv = 1.f / s;

  half8 h;
#pragma unroll
  for (int i = 0; i < 8; i++) h[i] = (_Float16)(e[i] * inv);
  ((half8*)dst)[tid] = h;
}

extern "C" void kernel_launch(void* const* d_in, const int* in_sizes, int n_in,
                              void* d_out, int out_size, void* d_ws, size_t ws_size,
                              hipStream_t stream) {
  const float* target = (const float*)d_in[0];
  const float* non_target = (const float*)d_in[1];
  const float* Wq = (const float*)d_in[2];
  const float* bq = (const float*)d_in[3];
  const float* Wk = (const float*)d_in[4];
  const float* bk = (const float*)d_in[5];
  const float* Wv = (const float*)d_in[6];
  const float* bv = (const float*)d_in[7];

  char* ws = (char*)d_ws;
  const size_t MB = 1ull << 20;
  _Float16* tgt16 = (_Float16*)(ws);             // 32 MiB
  _Float16* ntg16 = (_Float16*)(ws + 32 * MB);   // 32 MiB
  _Float16* S16 = (_Float16*)(ws);               // 64 MiB (over tgt16/ntg16, phase 3)
  _Float16* P16 = (_Float16*)(ws + 64 * MB);     // 64 MiB
  _Float16* Q16 = (_Float16*)(ws + 128 * MB);    // 32 MiB
  _Float16* K16 = (_Float16*)(ws + 160 * MB);    // 32 MiB
  _Float16* Vt16 = (_Float16*)(ws + 192 * MB);   // 32 MiB
  _Float16* Wq16 = (_Float16*)(ws + 224 * MB);   // 2 MiB
  _Float16* Wk16 = (_Float16*)(ws + 226 * MB);   // 2 MiB
  _Float16* Wv16 = (_Float16*)(ws + 228 * MB);   // 2 MiB

  const long nBig = 8l * 2048 * 1024;  // 16.78M
  const long nW = 1024l * 1024;

  // 1. casts
  cast_f32_f16<<<8192, 256, 0, stream>>>(target, tgt16, nBig);
  cast_f32_f16<<<8192, 256, 0, stream>>>(non_target, ntg16, nBig);
  cast_f32_f16<<<512, 256, 0, stream>>>(Wq, Wq16, nW);
  cast_f32_f16<<<512, 256, 0, stream>>>(Wk, Wk16, nW);
  cast_f32_f16<<<512, 256, 0, stream>>>(Wv, Wv16, nW);

  // 2. projections: [16384,1024] = [16384,1024] x [1024,1024]^T + bias
  gemm_bt<0><<<dim3(128, 8, 1), 256, 0, stream>>>(tgt16, Wq16, bq, Q16, 1024, 1024, 0, 0, 0);
  gemm_bt<0><<<dim3(128, 8, 1), 256, 0, stream>>>(ntg16, Wk16, bk, K16, 1024, 1024, 0, 0, 0);
  gemm_bt<1><<<dim3(128, 8, 1), 256, 0, stream>>>(ntg16, Wv16, bv, Vt16, 1024, 1024, 0, 0, 0);

  // 3. scores: per batch [2048,2048] = Q_b x K_b^T (fp16 out)
  gemm_bt<3><<<dim3(16, 16, 8), 256, 0, stream>>>(Q16, K16, nullptr, S16, 1024, 2048,
                                                  2048l * 1024, 2048l * 1024, 2048l * 2048);

  // 4. softmax rows -> P fp16
  softmax_rows<<<16384, 256, 0, stream>>>(S16, P16);

  // 5. out: per batch [2048,1024] = P_b x Vt_b^T (fp32 out to d_out)
  gemm_bt<2><<<dim3(16, 8, 8), 256, 0, stream>>>(P16, Vt16, nullptr, (float*)d_out, 2048, 1024,
                                                 2048l * 2048, 1024l * 2048, 2048l * 1024);
}